// Round 5
// baseline (203.138 us; speedup 1.0000x reference)
//
#include <hip/hip_runtime.h>

#define EPSILON 5.0f

constexpr int BLOCKS  = 2048;     // 8 blocks/CU on 256 CUs
constexpr int THREADS = 256;      // 4 waves/block

typedef float fx4 __attribute__((ext_vector_type(4)));

// Single fused kernel.
// Stage A: each wave processes PAIRS of consecutive rows (2 rows / iter),
//   software-pipelined one pair ahead (8 loads in flight during compute).
//   Features use nontemporal loads (zero reuse); means stay cacheable (2 MiB,
//   L2-resident). Labels prefetched one pair-iteration ahead.
// Stage B: per-block partial -> d_ws; last block (atomic counter) reduces all
//   partials in fixed order -> deterministic, saves the 2nd kernel launch.
__global__ __launch_bounds__(THREADS) void ncl_fused_kernel(
    const float* __restrict__ features,
    const float* __restrict__ means,
    const int* __restrict__ labels,
    float* __restrict__ partials,
    unsigned int* __restrict__ counter,
    float* __restrict__ out,
    int B, float invB)
{
    const int lane = threadIdx.x & 63;
    const int globalWave = blockIdx.x * (THREADS >> 6) + (threadIdx.x >> 6);
    const int totalWaves = gridDim.x * (THREADS >> 6);
    const int nPairs = B >> 1;                    // B is even (262144)

    const fx4* __restrict__ F = reinterpret_cast<const fx4*>(features);
    const fx4* __restrict__ M = reinterpret_cast<const fx4*>(means);

    float wsum = 0.0f;   // meaningful on lane 0 only

    int p = globalWave;
    int clsA = 0, clsB = 0;
    if (p < nPairs) { clsA = labels[2 * p]; clsB = labels[2 * p + 1]; }

    fx4 fa0{0,0,0,0}, fa1{0,0,0,0}, ma0{0,0,0,0}, ma1{0,0,0,0};
    fx4 fb0{0,0,0,0}, fb1{0,0,0,0}, mb0{0,0,0,0}, mb1{0,0,0,0};
    if (p < nPairs) {
        const fx4* fa = F + (size_t)(2 * p)     * 128;
        const fx4* fb = F + (size_t)(2 * p + 1) * 128;
        const fx4* ma = M + (size_t)clsA * 128;
        const fx4* mb = M + (size_t)clsB * 128;
        fa0 = __builtin_nontemporal_load(fa + lane);
        fa1 = __builtin_nontemporal_load(fa + lane + 64);
        fb0 = __builtin_nontemporal_load(fb + lane);
        fb1 = __builtin_nontemporal_load(fb + lane + 64);
        ma0 = ma[lane]; ma1 = ma[lane + 64];
        mb0 = mb[lane]; mb1 = mb[lane + 64];
    }
    // labels one pair ahead
    int nclsA = 0, nclsB = 0;
    {
        const int np = p + totalWaves;
        if (np < nPairs) { nclsA = labels[2 * np]; nclsB = labels[2 * np + 1]; }
    }

    while (p < nPairs) {
        const int np = p + totalWaves;

        // ---- prefetch next pair (labels already resolved) ----
        fx4 xfa0{0,0,0,0}, xfa1{0,0,0,0}, xma0{0,0,0,0}, xma1{0,0,0,0};
        fx4 xfb0{0,0,0,0}, xfb1{0,0,0,0}, xmb0{0,0,0,0}, xmb1{0,0,0,0};
        if (np < nPairs) {
            const fx4* fa = F + (size_t)(2 * np)     * 128;
            const fx4* fb = F + (size_t)(2 * np + 1) * 128;
            const fx4* ma = M + (size_t)nclsA * 128;
            const fx4* mb = M + (size_t)nclsB * 128;
            xfa0 = __builtin_nontemporal_load(fa + lane);
            xfa1 = __builtin_nontemporal_load(fa + lane + 64);
            xfb0 = __builtin_nontemporal_load(fb + lane);
            xfb1 = __builtin_nontemporal_load(fb + lane + 64);
            xma0 = ma[lane]; xma1 = ma[lane + 64];
            xmb0 = mb[lane]; xmb1 = mb[lane + 64];
        }
        // labels two pairs ahead
        int yclsA = 0, yclsB = 0;
        {
            const int pp = p + 2 * totalWaves;
            if (pp < nPairs) { yclsA = labels[2 * pp]; yclsB = labels[2 * pp + 1]; }
        }

        // ---- compute current pair (next pair's 8 loads in flight) ----
        fx4 da0 = fa0 - ma0, da1 = fa1 - ma1;
        fx4 db0 = fb0 - mb0, db1 = fb1 - mb1;
        float a0 = da0.x * da0.x, a1 = da0.y * da0.y,
              a2 = da0.z * da0.z, a3 = da0.w * da0.w;
        float b0 = db0.x * db0.x, b1 = db0.y * db0.y,
              b2 = db0.z * db0.z, b3 = db0.w * db0.w;
        a0 = fmaf(da1.x, da1.x, a0); a1 = fmaf(da1.y, da1.y, a1);
        a2 = fmaf(da1.z, da1.z, a2); a3 = fmaf(da1.w, da1.w, a3);
        b0 = fmaf(db1.x, db1.x, b0); b1 = fmaf(db1.y, db1.y, b1);
        b2 = fmaf(db1.z, db1.z, b2); b3 = fmaf(db1.w, db1.w, b3);
        float accA = (a0 + a1) + (a2 + a3);
        float accB = (b0 + b1) + (b2 + b3);

        #pragma unroll
        for (int off = 32; off > 0; off >>= 1) {
            accA += __shfl_xor(accA, off, 64);
            accB += __shfl_xor(accB, off, 64);
        }

        if (lane == 0) {
            wsum += fmaxf(EPSILON - sqrtf(accA), 0.0f);
            wsum += fmaxf(EPSILON - sqrtf(accB), 0.0f);
        }

        // ---- rotate pipeline ----
        fa0 = xfa0; fa1 = xfa1; ma0 = xma0; ma1 = xma1;
        fb0 = xfb0; fb1 = xfb1; mb0 = xmb0; mb1 = xmb1;
        nclsA = yclsA; nclsB = yclsB;
        p = np;
    }

    // ---- per-block partial ----
    __shared__ float s[THREADS >> 6];
    __shared__ bool lastBlock;
    const int wv = threadIdx.x >> 6;
    if (lane == 0) s[wv] = wsum;
    __syncthreads();
    if (threadIdx.x == 0) {
        float t = 0.0f;
        #pragma unroll
        for (int i = 0; i < (THREADS >> 6); ++i) t += s[i];
        partials[blockIdx.x] = t;
        __threadfence();                                   // release partial
        const unsigned int prev = atomicAdd(counter, 1u);  // device-scope
        lastBlock = (prev == (unsigned int)(gridDim.x - 1));
    }
    __syncthreads();

    // ---- last block: deterministic final reduce (fixed order) ----
    if (lastBlock) {
        __threadfence();                                   // acquire partials
        float t = 0.0f;
        for (int i = threadIdx.x; i < (int)gridDim.x; i += THREADS)
            t += partials[i];
        #pragma unroll
        for (int off = 32; off > 0; off >>= 1)
            t += __shfl_xor(t, off, 64);
        if (lane == 0) s[wv] = t;
        __syncthreads();
        if (threadIdx.x == 0) {
            float acc = 0.0f;
            #pragma unroll
            for (int i = 0; i < (THREADS >> 6); ++i) acc += s[i];
            out[0] = acc * invB;
        }
    }
}

extern "C" void kernel_launch(void* const* d_in, const int* in_sizes, int n_in,
                              void* d_out, int out_size, void* d_ws, size_t ws_size,
                              hipStream_t stream) {
    const float* features = (const float*)d_in[0];
    const float* means    = (const float*)d_in[1];
    const int*   labels   = (const int*)d_in[2];
    float* out = (float*)d_out;

    const int B = in_sizes[2];                 // one label per row
    float* partials = (float*)d_ws;            // BLOCKS floats
    unsigned int* counter = (unsigned int*)((char*)d_ws + BLOCKS * sizeof(float));

    // reset the completion counter (graph-capturable async memset)
    hipMemsetAsync(counter, 0, sizeof(unsigned int), stream);

    ncl_fused_kernel<<<BLOCKS, THREADS, 0, stream>>>(features, means, labels,
                                                     partials, counter, out,
                                                     B, 1.0f / (float)B);
}

// Round 6
// 99.237 us; speedup vs baseline: 2.0470x; 2.0470x over previous
//
#include <hip/hip_runtime.h>

#define EPSILON 5.0f

constexpr int BLOCKS  = 2048;     // 8 blocks/CU on 256 CUs
constexpr int THREADS = 256;      // 4 waves/block

typedef float fx4 __attribute__((ext_vector_type(4)));

// Stage 1: each wave processes PAIRS of consecutive rows (2 rows / iter),
// software-pipelined one pair ahead (8 loads in flight during compute).
// Features nontemporal (zero reuse); means cacheable (2 MiB, L2-resident).
// Labels (wave-uniform -> SGPR loads) prefetched one pair-iteration ahead.
// Tail: plain per-block partial -> separate finisher kernel (NO atomics/fences:
// round-5's fused tail + memset regressed 2x).
__global__ __launch_bounds__(THREADS) void ncl_partial_kernel(
    const float* __restrict__ features,
    const float* __restrict__ means,
    const int* __restrict__ labels,
    float* __restrict__ partials,
    int B)
{
    const int lane = threadIdx.x & 63;
    const int globalWave = blockIdx.x * (THREADS >> 6) + (threadIdx.x >> 6);
    const int totalWaves = gridDim.x * (THREADS >> 6);
    const int nPairs = B >> 1;                    // B is even (262144)

    const fx4* __restrict__ F = reinterpret_cast<const fx4*>(features);
    const fx4* __restrict__ M = reinterpret_cast<const fx4*>(means);

    float wsum = 0.0f;   // meaningful on lane 0 only

    int p = globalWave;
    int clsA = 0, clsB = 0;
    if (p < nPairs) { clsA = labels[2 * p]; clsB = labels[2 * p + 1]; }

    fx4 fa0{0,0,0,0}, fa1{0,0,0,0}, ma0{0,0,0,0}, ma1{0,0,0,0};
    fx4 fb0{0,0,0,0}, fb1{0,0,0,0}, mb0{0,0,0,0}, mb1{0,0,0,0};
    if (p < nPairs) {
        const fx4* fa = F + (size_t)(2 * p)     * 128;
        const fx4* fb = F + (size_t)(2 * p + 1) * 128;
        const fx4* ma = M + (size_t)clsA * 128;
        const fx4* mb = M + (size_t)clsB * 128;
        fa0 = __builtin_nontemporal_load(fa + lane);
        fa1 = __builtin_nontemporal_load(fa + lane + 64);
        fb0 = __builtin_nontemporal_load(fb + lane);
        fb1 = __builtin_nontemporal_load(fb + lane + 64);
        ma0 = ma[lane]; ma1 = ma[lane + 64];
        mb0 = mb[lane]; mb1 = mb[lane + 64];
    }
    // labels one pair ahead (SGPR, wave-uniform)
    int nclsA = 0, nclsB = 0;
    {
        const int np = p + totalWaves;
        if (np < nPairs) { nclsA = labels[2 * np]; nclsB = labels[2 * np + 1]; }
    }

    while (p < nPairs) {
        const int np = p + totalWaves;

        // ---- prefetch next pair (labels already resolved) ----
        fx4 xfa0{0,0,0,0}, xfa1{0,0,0,0}, xma0{0,0,0,0}, xma1{0,0,0,0};
        fx4 xfb0{0,0,0,0}, xfb1{0,0,0,0}, xmb0{0,0,0,0}, xmb1{0,0,0,0};
        if (np < nPairs) {
            const fx4* fa = F + (size_t)(2 * np)     * 128;
            const fx4* fb = F + (size_t)(2 * np + 1) * 128;
            const fx4* ma = M + (size_t)nclsA * 128;
            const fx4* mb = M + (size_t)nclsB * 128;
            xfa0 = __builtin_nontemporal_load(fa + lane);
            xfa1 = __builtin_nontemporal_load(fa + lane + 64);
            xfb0 = __builtin_nontemporal_load(fb + lane);
            xfb1 = __builtin_nontemporal_load(fb + lane + 64);
            xma0 = ma[lane]; xma1 = ma[lane + 64];
            xmb0 = mb[lane]; xmb1 = mb[lane + 64];
        }
        // labels two pairs ahead
        int yclsA = 0, yclsB = 0;
        {
            const int pp = p + 2 * totalWaves;
            if (pp < nPairs) { yclsA = labels[2 * pp]; yclsB = labels[2 * pp + 1]; }
        }

        // ---- compute current pair (next pair's 8 loads in flight) ----
        fx4 da0 = fa0 - ma0, da1 = fa1 - ma1;
        fx4 db0 = fb0 - mb0, db1 = fb1 - mb1;
        fx4 va = da0 * da0;  va = da1 * da1 + va;
        fx4 vb = db0 * db0;  vb = db1 * db1 + vb;
        float accA = (va.x + va.y) + (va.z + va.w);
        float accB = (vb.x + vb.y) + (vb.z + vb.w);

        #pragma unroll
        for (int off = 32; off > 0; off >>= 1) {
            accA += __shfl_xor(accA, off, 64);
            accB += __shfl_xor(accB, off, 64);
        }

        if (lane == 0) {
            wsum += fmaxf(EPSILON - sqrtf(accA), 0.0f);
            wsum += fmaxf(EPSILON - sqrtf(accB), 0.0f);
        }

        // ---- rotate pipeline ----
        fa0 = xfa0; fa1 = xfa1; ma0 = xma0; ma1 = xma1;
        fb0 = xfb0; fb1 = xfb1; mb0 = xmb0; mb1 = xmb1;
        nclsA = yclsA; nclsB = yclsB;
        p = np;
    }

    __shared__ float s[THREADS >> 6];
    const int wv = threadIdx.x >> 6;
    if (lane == 0) s[wv] = wsum;
    __syncthreads();
    if (threadIdx.x == 0) {
        float t = 0.0f;
        #pragma unroll
        for (int i = 0; i < (THREADS >> 6); ++i) t += s[i];
        partials[blockIdx.x] = t;
    }
}

// Stage 2: single block reduces BLOCKS partials, writes mean.
__global__ __launch_bounds__(THREADS) void ncl_final_kernel(
    const float* __restrict__ partials,
    int n,
    float* __restrict__ out,
    float invB)
{
    float t = 0.0f;
    for (int i = threadIdx.x; i < n; i += THREADS) t += partials[i];

    #pragma unroll
    for (int off = 32; off > 0; off >>= 1)
        t += __shfl_xor(t, off, 64);

    __shared__ float s[THREADS >> 6];
    const int lane = threadIdx.x & 63;
    const int wv   = threadIdx.x >> 6;
    if (lane == 0) s[wv] = t;
    __syncthreads();
    if (threadIdx.x == 0) {
        float acc = 0.0f;
        #pragma unroll
        for (int i = 0; i < (THREADS >> 6); ++i) acc += s[i];
        out[0] = acc * invB;
    }
}

extern "C" void kernel_launch(void* const* d_in, const int* in_sizes, int n_in,
                              void* d_out, int out_size, void* d_ws, size_t ws_size,
                              hipStream_t stream) {
    const float* features = (const float*)d_in[0];
    const float* means    = (const float*)d_in[1];
    const int*   labels   = (const int*)d_in[2];
    float* out = (float*)d_out;

    const int B = in_sizes[2];        // one label per row
    float* partials = (float*)d_ws;   // BLOCKS floats

    ncl_partial_kernel<<<BLOCKS, THREADS, 0, stream>>>(features, means, labels,
                                                       partials, B);
    ncl_final_kernel<<<1, THREADS, 0, stream>>>(partials, BLOCKS, out,
                                                1.0f / (float)B);
}